// Round 5
// baseline (22.198 us; speedup 1.0000x reference)
//
#include <hip/hip_runtime.h>

#define B 8
#define S 2048
#define NBPS 64                        // inter blocks per sample
#define NBLK (B * NBPS)                // 512 total blocks, 2 per CU
#define TPB 256
#define LPB (S / NBPS)                 // 32 loss elems per block

// ---------------------------------------------------------------------------
// Workspace (every slot rewritten every launch -> re-poison safe, no atomics):
//   [0,32)       int   n_buf[8]
//   [64,2112)    float partial[512]       intersection per-block sums
//   [2176,12416) float acc2[5][512]       loss per-block sums (transposed)
// ---------------------------------------------------------------------------

__global__ __launch_bounds__(TPB) void mega_kernel(
    const float2* __restrict__ point_pred,
    const float2* __restrict__ orient_pred,
    const float4* __restrict__ class_pred,
    const float*  __restrict__ target_seq,
    const int*    __restrict__ padding_mask,
    int*   __restrict__ n_buf,
    float* __restrict__ partial,    // [512]
    float* __restrict__ acc2)       // [5][512]
{
    __shared__ float2 sp[S];                 // 16 KB
    __shared__ float red[TPB / 64][1];
    __shared__ int wsum[TPB / 64], woff[TPB / 64], nTot;

    const int blk = blockIdx.x;
    const int tid = threadIdx.x;
    const int lane = tid & 63, wv = tid >> 6;
    const int b = blk >> 6;                  // blk / NBPS
    const int iblk = blk & (NBPS - 1);
    const int base = b * S;
    const int e0 = tid * 8;                  // 8 contiguous elems per thread

    // ---- staged loads: mask (int4 x2), points (float4 x4), target rows ----
    const int4* pm4 = (const int4*)(padding_mask + base + e0);
    const int4 ma = pm4[0], mb = pm4[1];
    const float4* tr4 = (const float4*)(target_seq + (size_t)(base + e0) * 5);
    float4 tq[10];
    #pragma unroll
    for (int k = 0; k < 10; ++k) tq[k] = tr4[k];
    float t4v[8];
    t4v[0] = tq[1].x; t4v[1] = tq[2].y; t4v[2] = tq[3].z; t4v[3] = tq[4].w;
    t4v[4] = tq[6].x; t4v[5] = tq[7].y; t4v[6] = tq[8].z; t4v[7] = tq[9].w;
    const float4* pq4 = (const float4*)(point_pred + base + e0);
    const float4 pa = pq4[0], pb = pq4[1], pc = pq4[2], pd = pq4[3];
    float2 p[8];
    p[0] = make_float2(pa.x, pa.y); p[1] = make_float2(pa.z, pa.w);
    p[2] = make_float2(pb.x, pb.y); p[3] = make_float2(pb.z, pb.w);
    p[4] = make_float2(pc.x, pc.y); p[5] = make_float2(pc.z, pc.w);
    p[6] = make_float2(pd.x, pd.y); p[7] = make_float2(pd.z, pd.w);
    int f[8];
    f[0] = (ma.x == 0 && (int)t4v[0] != 0) ? 1 : 0;
    f[1] = (ma.y == 0 && (int)t4v[1] != 0) ? 1 : 0;
    f[2] = (ma.z == 0 && (int)t4v[2] != 0) ? 1 : 0;
    f[3] = (ma.w == 0 && (int)t4v[3] != 0) ? 1 : 0;
    f[4] = (mb.x == 0 && (int)t4v[4] != 0) ? 1 : 0;
    f[5] = (mb.y == 0 && (int)t4v[5] != 0) ? 1 : 0;
    f[6] = (mb.z == 0 && (int)t4v[6] != 0) ? 1 : 0;
    f[7] = (mb.w == 0 && (int)t4v[7] != 0) ? 1 : 0;

    // ---- per-block loss slice: threads 0..31 handle elems iblk*32+t ----
    float cls_a = 0.f, pt_a = 0.f, or_a = 0.f, v_a = 0.f, nn_a = 0.f;
    if (tid < LPB) {
        const int idx = base + iblk * LPB + tid;
        const bool valid = (padding_mask[idx] == 0);
        const float* row = target_seq + (size_t)idx * 5;
        const float t4 = row[4];
        const int tc = (int)t4;
        const bool nn = valid && (tc != 0);
        if (valid) {
            const float4 cl = class_pred[idx];
            const float m = fmaxf(fmaxf(cl.x, cl.y), fmaxf(cl.z, cl.w));
            const float lse = m + logf(expf(cl.x - m) + expf(cl.y - m) +
                                       expf(cl.z - m) + expf(cl.w - m));
            const float ct = (tc == 0) ? cl.x : (tc == 1) ? cl.y : (tc == 2) ? cl.z : cl.w;
            cls_a = lse - ct;
            v_a = 1.f;
        }
        if (nn) {
            const float2 pp = point_pred[idx];
            const float dx = (pp.x - row[0]) * (1.0f / 224.0f);
            const float dy = (pp.y - row[1]) * (1.0f / 224.0f);
            const float adx = fabsf(dx), ady = fabsf(dy);
            const float l0 = (adx < 1.f) ? 0.5f * dx * dx : adx - 0.5f;
            const float l1 = (ady < 1.f) ? 0.5f * dy * dy : ady - 0.5f;
            pt_a = 0.5f * (l0 + l1);
            const float2 op = orient_pred[idx];
            or_a = 1.f - (op.x * row[2] + op.y * row[3]);
            nn_a = 1.f;
        }
    }
    if (wv == 0) {                           // lanes 32..63 carry zeros
        #pragma unroll
        for (int off = 32; off > 0; off >>= 1) {
            cls_a += __shfl_down(cls_a, (unsigned)off, 64);
            pt_a  += __shfl_down(pt_a,  (unsigned)off, 64);
            or_a  += __shfl_down(or_a,  (unsigned)off, 64);
            v_a   += __shfl_down(v_a,   (unsigned)off, 64);
            nn_a  += __shfl_down(nn_a,  (unsigned)off, 64);
        }
        if (lane == 0) {
            acc2[0 * NBLK + blk] = cls_a;
            acc2[1 * NBLK + blk] = pt_a;
            acc2[2 * NBLK + blk] = or_a;
            acc2[3 * NBLK + blk] = v_a;
            acc2[4 * NBLK + blk] = nn_a;
        }
    }

    // ---- block scan over per-thread counts (stable compaction) ----
    const int c = f[0]+f[1]+f[2]+f[3]+f[4]+f[5]+f[6]+f[7];
    int inc = c;
    #pragma unroll
    for (int off = 1; off < 64; off <<= 1) {
        int u = __shfl_up(inc, (unsigned)off, 64);
        if (lane >= off) inc += u;
    }
    if (lane == 63) wsum[wv] = inc;
    __syncthreads();
    if (tid == 0) {
        int run = 0;
        #pragma unroll
        for (int w = 0; w < TPB / 64; ++w) { woff[w] = run; run += wsum[w]; }
        nTot = run;
    }
    __syncthreads();
    int pos = woff[wv] + inc - c;            // exclusive prefix
    #pragma unroll
    for (int k = 0; k < 8; ++k) { if (f[k]) sp[pos++] = p[k]; }
    __syncthreads();

    const int n = nTot;
    if (iblk == 0 && tid == 0) n_buf[b] = n;

    // ---- pair loop ----
    float local = 0.f;
    if (n >= 4) {
        const int n_seg = n - 1;
        for (int i = iblk; i < n_seg - 2; i += NBPS) {
            const float2 q1 = sp[i], q2 = sp[i + 1];
            const float e12x = q2.x - q1.x, e12y = q2.y - q1.y;
            const int jmax = (i == 0) ? n_seg - 1 : n_seg;   // wrap-pair excl.
            for (int j = i + 2 + tid; j < jmax; j += TPB) {
                const float2 q3 = sp[j], q4 = sp[j + 1];
                const float e34x = q4.x - q3.x, e34y = q4.y - q3.y;
                const float ce = e12x * e34y - e12y * e34x;
                const float rx = q1.x - q3.x, ry = q1.y - q3.y;
                const float d1 = e34x * ry - e34y * rx;
                const float d3 = e12y * rx - e12x * ry;
                const float d2 = d1 - ce;
                const float d4 = d3 + ce;
                const float ea = __expf(d1 * d2 * 0.01f);
                const float eb = __expf(d3 * d4 * 0.01f);
                // sigmoid(z1)*sigmoid(z2) = 1/((1+ea)(1+eb)); inf->rcp->0 ok
                local += __builtin_amdgcn_rcpf((1.f + ea) * (1.f + eb));
            }
        }
    }
    #pragma unroll
    for (int off = 32; off > 0; off >>= 1)
        local += __shfl_down(local, (unsigned)off, 64);
    if (lane == 0) red[wv][0] = local;
    __syncthreads();
    if (tid == 0)
        partial[blk] = red[0][0] + red[1][0] + red[2][0] + red[3][0];
}

// ---------------------------------------------------------------------------
// Finalize: 1 wave, no barriers. Kernel boundary = cross-XCD visibility.
// ---------------------------------------------------------------------------
__global__ __launch_bounds__(64) void finalize_kernel(
    const float* __restrict__ acc2,      // [5][512]
    const int* __restrict__ n_buf,
    const float* __restrict__ partial,   // [512]
    float* __restrict__ out)
{
    const int lane = threadIdx.x;        // 0..63

    const float4* p4 = (const float4*)partial;
    const float4 u = p4[lane * 2], v = p4[lane * 2 + 1];
    float s = (u.x + u.y) + (u.z + u.w) + (v.x + v.y) + (v.z + v.w);

    float a[5];
    #pragma unroll
    for (int ch = 0; ch < 5; ++ch) {
        const float4* c4 = (const float4*)(acc2 + ch * NBLK);
        const float4 x = c4[lane * 2], y = c4[lane * 2 + 1];
        a[ch] = (x.x + x.y) + (x.z + x.w) + (y.x + y.y) + (y.z + y.w);
    }

    #pragma unroll
    for (int off = 32; off > 0; off >>= 1) {
        s += __shfl_down(s, (unsigned)off, 64);
        #pragma unroll
        for (int ch = 0; ch < 5; ++ch)
            a[ch] += __shfl_down(a[ch], (unsigned)off, 64);
    }

    if (lane == 0) {
        const float inter_sum = s;
        long long cnt = 0;
        #pragma unroll
        for (int b2 = 0; b2 < B; ++b2) {
            const int n = n_buf[b2];
            if (n >= 4) {
                const long long ns = n - 1;
                cnt += (ns - 1) * (ns - 2) / 2 - 1;
            }
        }
        const float cls_loss = a[0] / fmaxf(a[3], 1.f);
        const float pt_loss = a[1] / fmaxf(a[4], 1.f);
        const float orient_loss = a[2] / fmaxf(a[4], 1.f);
        const float intersect_loss = (cnt > 0) ? inter_sum / (float)cnt : 0.f;
        out[0] = 1.0f * pt_loss + 0.5f * orient_loss +
                 1.0f * cls_loss + 0.1f * intersect_loss;
        out[1] = pt_loss;
        out[2] = orient_loss;
        out[3] = cls_loss;
        out[4] = intersect_loss;
    }
}

extern "C" void kernel_launch(void* const* d_in, const int* in_sizes, int n_in,
                              void* d_out, int out_size, void* d_ws, size_t ws_size,
                              hipStream_t stream) {
    (void)in_sizes; (void)n_in; (void)out_size; (void)ws_size;
    const float2* point_pred  = (const float2*)d_in[0];
    const float2* orient_pred = (const float2*)d_in[1];
    const float4* class_pred  = (const float4*)d_in[2];
    const float*  target_seq  = (const float*)d_in[3];
    const int*    padding_mask = (const int*)d_in[4];

    int*   n_buf   = (int*)d_ws;
    float* partial = (float*)((char*)d_ws + 64);
    float* acc2    = (float*)((char*)d_ws + 2176);

    mega_kernel<<<NBLK, TPB, 0, stream>>>(point_pred, orient_pred, class_pred,
                                          target_seq, padding_mask,
                                          n_buf, partial, acc2);
    finalize_kernel<<<1, 64, 0, stream>>>(acc2, n_buf, partial, (float*)d_out);
}

// Round 6
// 19.760 us; speedup vs baseline: 1.1234x; 1.1234x over previous
//
#include <hip/hip_runtime.h>

#define B 8
#define S 2048
#define NBPS 128                       // inter blocks per sample
#define NBLK_INTER (B * NBPS)          // 1024
#define NBLK_LOSS 64
#define NBLK_TOTAL (NBLK_INTER + NBLK_LOSS)   // 1088
#define TPB 256

// ---------------------------------------------------------------------------
// Workspace (every slot rewritten every launch -> re-poison safe, no atomics):
//   [0,32)       int   n_buf[8]
//   [64,4160)    float partial[1024]   intersection per-block sums
//   [4224,5504)  float acc2[5][64]     loss per-block sums (transposed)
// ---------------------------------------------------------------------------

__global__ __launch_bounds__(TPB) void mega_kernel(
    const float2* __restrict__ point_pred,
    const float2* __restrict__ orient_pred,
    const float4* __restrict__ class_pred,
    const float*  __restrict__ target_seq,
    const int*    __restrict__ padding_mask,
    int*   __restrict__ n_buf,
    float* __restrict__ partial,    // [1024]
    float* __restrict__ acc2)       // [5][64]
{
    __shared__ float2 sp[S];                 // 16 KB
    __shared__ float red[TPB / 64][5];
    __shared__ int wsum[TPB / 64], woff[TPB / 64], nTot;

    const int blk = blockIdx.x;
    const int tid = threadIdx.x;
    const int lane = tid & 63, wv = tid >> 6;

    if (blk < NBLK_INTER) {
        // ================= intersection role =================
        const int b = blk >> 7;              // blk / NBPS
        const int iblk = blk & (NBPS - 1);
        const int base = b * S;
        const int e0 = tid * 8;              // 8 contiguous elems per thread

        // ---- staged loads: mask (int4 x2), target rows (float4 x10),
        //      points (float4 x4) ----
        const int4* pm4 = (const int4*)(padding_mask + base + e0);
        const int4 ma = pm4[0], mb = pm4[1];
        const float4* tr4 = (const float4*)(target_seq + (size_t)(base + e0) * 5);
        float4 tq[10];
        #pragma unroll
        for (int k = 0; k < 10; ++k) tq[k] = tr4[k];
        float t4v[8];
        t4v[0] = tq[1].x; t4v[1] = tq[2].y; t4v[2] = tq[3].z; t4v[3] = tq[4].w;
        t4v[4] = tq[6].x; t4v[5] = tq[7].y; t4v[6] = tq[8].z; t4v[7] = tq[9].w;
        const float4* pq4 = (const float4*)(point_pred + base + e0);
        const float4 pa = pq4[0], pb = pq4[1], pc = pq4[2], pd = pq4[3];
        float2 p[8];
        p[0] = make_float2(pa.x, pa.y); p[1] = make_float2(pa.z, pa.w);
        p[2] = make_float2(pb.x, pb.y); p[3] = make_float2(pb.z, pb.w);
        p[4] = make_float2(pc.x, pc.y); p[5] = make_float2(pc.z, pc.w);
        p[6] = make_float2(pd.x, pd.y); p[7] = make_float2(pd.z, pd.w);
        int f[8];
        f[0] = (ma.x == 0 && (int)t4v[0] != 0) ? 1 : 0;
        f[1] = (ma.y == 0 && (int)t4v[1] != 0) ? 1 : 0;
        f[2] = (ma.z == 0 && (int)t4v[2] != 0) ? 1 : 0;
        f[3] = (ma.w == 0 && (int)t4v[3] != 0) ? 1 : 0;
        f[4] = (mb.x == 0 && (int)t4v[4] != 0) ? 1 : 0;
        f[5] = (mb.y == 0 && (int)t4v[5] != 0) ? 1 : 0;
        f[6] = (mb.z == 0 && (int)t4v[6] != 0) ? 1 : 0;
        f[7] = (mb.w == 0 && (int)t4v[7] != 0) ? 1 : 0;

        // ---- block scan over per-thread counts (stable compaction) ----
        const int c = f[0]+f[1]+f[2]+f[3]+f[4]+f[5]+f[6]+f[7];
        int inc = c;
        #pragma unroll
        for (int off = 1; off < 64; off <<= 1) {
            int u = __shfl_up(inc, (unsigned)off, 64);
            if (lane >= off) inc += u;
        }
        if (lane == 63) wsum[wv] = inc;
        __syncthreads();
        if (tid == 0) {
            int run = 0;
            #pragma unroll
            for (int w = 0; w < TPB / 64; ++w) { woff[w] = run; run += wsum[w]; }
            nTot = run;
        }
        __syncthreads();
        int pos = woff[wv] + inc - c;        // exclusive prefix
        #pragma unroll
        for (int k = 0; k < 8; ++k) { if (f[k]) sp[pos++] = p[k]; }
        __syncthreads();

        const int n = nTot;
        if (iblk == 0 && tid == 0) n_buf[b] = n;

        // ---- pair loop ----
        float local = 0.f;
        if (n >= 4) {
            const int n_seg = n - 1;
            for (int i = iblk; i < n_seg - 2; i += NBPS) {
                const float2 q1 = sp[i], q2 = sp[i + 1];
                const float e12x = q2.x - q1.x, e12y = q2.y - q1.y;
                const int jmax = (i == 0) ? n_seg - 1 : n_seg;  // wrap-pair excl.
                for (int j = i + 2 + tid; j < jmax; j += TPB) {
                    const float2 q3 = sp[j], q4 = sp[j + 1];
                    const float e34x = q4.x - q3.x, e34y = q4.y - q3.y;
                    const float ce = e12x * e34y - e12y * e34x;
                    const float rx = q1.x - q3.x, ry = q1.y - q3.y;
                    const float d1 = e34x * ry - e34y * rx;
                    const float d3 = e12y * rx - e12x * ry;
                    const float d2 = d1 - ce;
                    const float d4 = d3 + ce;
                    const float ea = __expf(d1 * d2 * 0.01f);
                    const float eb = __expf(d3 * d4 * 0.01f);
                    // sigmoid(z1)*sigmoid(z2) = 1/((1+ea)(1+eb)); inf->rcp->0 ok
                    local += __builtin_amdgcn_rcpf((1.f + ea) * (1.f + eb));
                }
            }
        }
        #pragma unroll
        for (int off = 32; off > 0; off >>= 1)
            local += __shfl_down(local, (unsigned)off, 64);
        if (lane == 0) red[wv][0] = local;
        __syncthreads();
        if (tid == 0)
            partial[blk] = red[0][0] + red[1][0] + red[2][0] + red[3][0];
    } else {
        // ================= per-element loss role =================
        const int idx = (blk - NBLK_INTER) * TPB + tid;   // [0, B*S)
        const bool valid = (padding_mask[idx] == 0);
        const float t4 = target_seq[(size_t)idx * 5 + 4];
        const int tc = (int)t4;
        const bool nn = valid && (tc != 0);
        float cls_a = 0.f, pt_a = 0.f, or_a = 0.f, v_a = 0.f, nn_a = 0.f;
        if (valid) {
            const float4 cl = class_pred[idx];
            const float m = fmaxf(fmaxf(cl.x, cl.y), fmaxf(cl.z, cl.w));
            const float lse = m + logf(expf(cl.x - m) + expf(cl.y - m) +
                                       expf(cl.z - m) + expf(cl.w - m));
            const float ct = (tc == 0) ? cl.x : (tc == 1) ? cl.y : (tc == 2) ? cl.z : cl.w;
            cls_a = lse - ct;
            v_a = 1.f;
        }
        if (nn) {
            const float2 pp = point_pred[idx];
            const float tx = target_seq[(size_t)idx * 5 + 0];
            const float ty = target_seq[(size_t)idx * 5 + 1];
            const float dx = (pp.x - tx) * (1.0f / 224.0f);
            const float dy = (pp.y - ty) * (1.0f / 224.0f);
            const float adx = fabsf(dx), ady = fabsf(dy);
            const float l0 = (adx < 1.f) ? 0.5f * dx * dx : adx - 0.5f;
            const float l1 = (ady < 1.f) ? 0.5f * dy * dy : ady - 0.5f;
            pt_a = 0.5f * (l0 + l1);
            const float2 op = orient_pred[idx];
            const float ox = target_seq[(size_t)idx * 5 + 2];
            const float oy = target_seq[(size_t)idx * 5 + 3];
            or_a = 1.f - (op.x * ox + op.y * oy);
            nn_a = 1.f;
        }
        #pragma unroll
        for (int off = 32; off > 0; off >>= 1) {
            cls_a += __shfl_down(cls_a, (unsigned)off, 64);
            pt_a  += __shfl_down(pt_a,  (unsigned)off, 64);
            or_a  += __shfl_down(or_a,  (unsigned)off, 64);
            v_a   += __shfl_down(v_a,   (unsigned)off, 64);
            nn_a  += __shfl_down(nn_a,  (unsigned)off, 64);
        }
        if (lane == 0) {
            red[wv][0] = cls_a; red[wv][1] = pt_a; red[wv][2] = or_a;
            red[wv][3] = v_a;   red[wv][4] = nn_a;
        }
        __syncthreads();
        if (tid == 0) {
            const int lb = blk - NBLK_INTER;     // [0,64)
            #pragma unroll
            for (int c5 = 0; c5 < 5; ++c5)
                acc2[c5 * NBLK_LOSS + lb] =
                    red[0][c5] + red[1][c5] + red[2][c5] + red[3][c5];
        }
    }
}

// ---------------------------------------------------------------------------
// Finalize: 1 wave, no barriers. Kernel boundary = cross-XCD visibility.
// ---------------------------------------------------------------------------
__global__ __launch_bounds__(64) void finalize_kernel(
    const float* __restrict__ acc2,      // [5][64]
    const int* __restrict__ n_buf,
    const float* __restrict__ partial,   // [1024]
    float* __restrict__ out)
{
    const int lane = threadIdx.x;        // 0..63

    const float4* p4 = (const float4*)partial;   // 256 float4
    float s = 0.f;
    #pragma unroll
    for (int k = 0; k < 4; ++k) {
        const float4 u = p4[lane * 4 + k];
        s += (u.x + u.y) + (u.z + u.w);
    }

    float a[5];
    #pragma unroll
    for (int ch = 0; ch < 5; ++ch) a[ch] = acc2[ch * NBLK_LOSS + lane];

    #pragma unroll
    for (int off = 32; off > 0; off >>= 1) {
        s += __shfl_down(s, (unsigned)off, 64);
        #pragma unroll
        for (int ch = 0; ch < 5; ++ch)
            a[ch] += __shfl_down(a[ch], (unsigned)off, 64);
    }

    if (lane == 0) {
        const float inter_sum = s;
        long long cnt = 0;
        #pragma unroll
        for (int b2 = 0; b2 < B; ++b2) {
            const int n = n_buf[b2];
            if (n >= 4) {
                const long long ns = n - 1;
                cnt += (ns - 1) * (ns - 2) / 2 - 1;
            }
        }
        const float cls_loss = a[0] / fmaxf(a[3], 1.f);
        const float pt_loss = a[1] / fmaxf(a[4], 1.f);
        const float orient_loss = a[2] / fmaxf(a[4], 1.f);
        const float intersect_loss = (cnt > 0) ? inter_sum / (float)cnt : 0.f;
        out[0] = 1.0f * pt_loss + 0.5f * orient_loss +
                 1.0f * cls_loss + 0.1f * intersect_loss;
        out[1] = pt_loss;
        out[2] = orient_loss;
        out[3] = cls_loss;
        out[4] = intersect_loss;
    }
}

extern "C" void kernel_launch(void* const* d_in, const int* in_sizes, int n_in,
                              void* d_out, int out_size, void* d_ws, size_t ws_size,
                              hipStream_t stream) {
    (void)in_sizes; (void)n_in; (void)out_size; (void)ws_size;
    const float2* point_pred  = (const float2*)d_in[0];
    const float2* orient_pred = (const float2*)d_in[1];
    const float4* class_pred  = (const float4*)d_in[2];
    const float*  target_seq  = (const float*)d_in[3];
    const int*    padding_mask = (const int*)d_in[4];

    int*   n_buf   = (int*)d_ws;
    float* partial = (float*)((char*)d_ws + 64);
    float* acc2    = (float*)((char*)d_ws + 4224);

    mega_kernel<<<NBLK_TOTAL, TPB, 0, stream>>>(point_pred, orient_pred,
                                                class_pred, target_seq,
                                                padding_mask,
                                                n_buf, partial, acc2);
    finalize_kernel<<<1, 64, 0, stream>>>(acc2, n_buf, partial, (float*)d_out);
}